// Round 6
// baseline (254.989 us; speedup 1.0000x reference)
//
#include <hip/hip_runtime.h>

// SimpleSAGE v2: frontier-COMPACTED 2-layer mean-SAGE + center readout.
// v1 profile showed k_agg dispatches carrying ~32 MB of L2 writebacks from a
// 13.3 MB memset + 12.8 MB node-indexed agg table, and a full 800k-edge scan
// to find the ~8k center-inbound edges. v2: slot-compacted aggregation table
// (4 MB cap, ~2.2 MB used), explicit center-edge list built during k_mark,
// degree counted only for frontier nodes during the aggregation scan.

constexpr int NN  = 50000;   // nodes
constexpr int NG  = 500;     // graphs
constexpr int NPG = 100;     // nodes per graph
constexpr int NE  = 800000;  // edges
constexpr int D   = 64;      // feature dim
constexpr int SCAP = 16384;  // frontier slot cap (expected ~8.5k)
constexpr int ECAP = 16384;  // center-edge cap   (expected ~8k)

// ---- workspace byte offsets ----
constexpr size_t OFF_AGGC  = 0;                                  // SCAP*D f32 (4 MB)
constexpr size_t OFF_AGG2  = OFF_AGGC + (size_t)SCAP * D * 4;    // NG*D f32
constexpr size_t OFF_FLAG  = OFF_AGG2 + (size_t)NG * D * 4;      // NN i32
constexpr size_t OFF_DEGC  = OFF_FLAG + (size_t)NN * 4;          // SCAP i32
constexpr size_t OFF_CNT   = OFF_DEGC + (size_t)SCAP * 4;        // 2 i32 (+pad)
constexpr size_t OFF_NODE  = OFF_CNT + 16;                       // SCAP i32
constexpr size_t OFF_ELIST = OFF_NODE + (size_t)SCAP * 4;        // ECAP int2
constexpr size_t MEMSET_BYTES = OFF_NODE - OFF_AGG2;             // agg2+flag+degC+cnt

// flag encoding: bit0 = center, bit1 = frontier (needs h1), bits2.. = slot id

__global__ void k_init(const int* __restrict__ cpos, int* __restrict__ flag) {
  int g = blockIdx.x * blockDim.x + threadIdx.x;
  if (g < NG) flag[g * NPG + cpos[g]] = 3;
}

// Scan edges: mark frontier (srcs of center-inbound edges) and append those
// edges to elist (wave-aggregated atomic append).
__global__ void k_mark(const int* __restrict__ src, const int* __restrict__ dst,
                       int* __restrict__ flag, int2* __restrict__ elist,
                       int* __restrict__ cnt) {
  int lane = threadIdx.x & 63;
  int wid  = (blockIdx.x * blockDim.x + threadIdx.x) >> 6;
  int nw   = (gridDim.x * blockDim.x) >> 6;
  for (int base = wid * 64; base < NE; base += nw * 64) {
    int e = base + lane;                 // NE % 64 == 0
    int d = dst[e];
    bool m = (flag[d] & 1) != 0;         // dst is a center
    int s = 0;
    if (m) s = src[e];
    unsigned long long bal = __ballot(m);
    if (m) atomicOr(&flag[s], 2);
    int n = __popcll(bal);
    if (n) {
      int basei;
      if (lane == 0) basei = atomicAdd(&cnt[0], n);
      basei = __shfl(basei, 0);
      if (m) {
        int idx = basei + __popcll(bal & ((1ull << lane) - 1));
        if (idx < ECAP) elist[idx] = make_int2(s, d);
      }
    }
  }
}

// Assign compact slots to frontier nodes; zero their aggC rows.
__global__ void k_compact(int* __restrict__ flag, int* __restrict__ nodelist,
                          float* __restrict__ aggC, int* __restrict__ cnt) {
  int v = blockIdx.x * blockDim.x + threadIdx.x;
  int lane = threadIdx.x & 63;
  bool m = false;
  int f = 0;
  if (v < NN) { f = flag[v]; m = (f & 2) != 0; }
  unsigned long long bal = __ballot(m);
  int n = __popcll(bal);
  if (n) {
    int basei;
    if (lane == 0) basei = atomicAdd(&cnt[1], n);
    basei = __shfl(basei, 0);
    if (m) {
      int slot = basei + __popcll(bal & ((1ull << lane) - 1));
      if (slot < SCAP) {
        flag[v] = f | (slot << 2);
        nodelist[slot] = v;
        float4 z = make_float4(0.f, 0.f, 0.f, 0.f);
        float4* row = (float4*)&aggC[(size_t)slot * D];
#pragma unroll
        for (int i = 0; i < D / 4; i++) row[i] = z;
      }
    }
  }
}

// Scan edges: for frontier destinations, gather x[src] into aggC[slot(dst)]
// and count the full in-degree of the frontier node.
__global__ void k_agg2(const int* __restrict__ src, const int* __restrict__ dst,
                       const int* __restrict__ flag, const float* __restrict__ x,
                       float* __restrict__ aggC, int* __restrict__ degC) {
  int lane = threadIdx.x & 63;
  int wid  = (blockIdx.x * blockDim.x + threadIdx.x) >> 6;
  int nw   = (gridDim.x * blockDim.x) >> 6;
  for (int base = wid * 64; base < NE; base += nw * 64) {
    int e = base + lane;
    int d = dst[e];
    int f = flag[d];
    bool m = (f & 2) != 0;
    int s = 0;
    if (m) s = src[e];
    unsigned long long bal = __ballot(m);
    while (bal) {
      int b = __ffsll(bal) - 1;
      bal &= bal - 1;
      int ss = __shfl(s, b);
      int sl = __shfl(f, b) >> 2;
      float v = x[(size_t)ss * D + lane];
      atomicAdd(&aggC[(size_t)sl * D + lane], v);
      if (lane == 0) atomicAdd(&degC[sl], 1);
    }
  }
}

// h1[slot] = relu(Wl1*(aggC[slot]/max(deg,1)) + bl1 + Wr1*x[node]) in-place.
__global__ void k_sage1(const float* __restrict__ x, const int* __restrict__ nodelist,
                        const int* __restrict__ degC, float* __restrict__ aggC,
                        const float* __restrict__ Wl, const float* __restrict__ bl,
                        const float* __restrict__ Wr, const int* __restrict__ cnt) {
  __shared__ float sWl[D * 65];
  __shared__ float sWr[D * 65];
  __shared__ float sbl[D];
  int tid = threadIdx.x;
  for (int i = tid; i < D * D; i += blockDim.x) {
    int r = i >> 6, c = i & 63;
    sWl[r * 65 + c] = Wl[i];
    sWr[r * 65 + c] = Wr[i];
  }
  if (tid < D) sbl[tid] = bl[tid];
  __syncthreads();

  int scnt = cnt[1];
  if (scnt > SCAP) scnt = SCAP;
  int lane = tid & 63;
  int wid  = (blockIdx.x * blockDim.x + tid) >> 6;
  int nw   = (gridDim.x * blockDim.x) >> 6;
  for (int slot = wid; slot < scnt; slot += nw) {
    int v = nodelist[slot];
    float dg = (float)degC[slot];
    if (dg < 1.f) dg = 1.f;
    float m  = aggC[(size_t)slot * D + lane] / dg;
    float xv = x[(size_t)v * D + lane];
    float h  = sbl[lane];
#pragma unroll
    for (int k = 0; k < D; k++) {
      h += sWl[lane * 65 + k] * __shfl(m, k) + sWr[lane * 65 + k] * __shfl(xv, k);
    }
    aggC[(size_t)slot * D + lane] = fmaxf(h, 0.f);  // h1 in-place
  }
}

// Process the compacted center-edge list: agg2[graph(dst)] += h1[slot(src)].
__global__ void k_agg1(const int2* __restrict__ elist, const int* __restrict__ flag,
                       const float* __restrict__ aggC, float* __restrict__ agg2,
                       const int* __restrict__ cnt) {
  int ecnt = cnt[0];
  if (ecnt > ECAP) ecnt = ECAP;
  int lane = threadIdx.x & 63;
  int wid  = (blockIdx.x * blockDim.x + threadIdx.x) >> 6;
  int nw   = (gridDim.x * blockDim.x) >> 6;
  for (int i = wid; i < ecnt; i += nw) {
    int2 ed = elist[i];
    int sl = flag[ed.x] >> 2;
    int g  = ed.y / NPG;
    atomicAdd(&agg2[(size_t)g * D + lane], aggC[(size_t)sl * D + lane]);
  }
}

// Per graph: h2 = relu(Wl2*(agg2[g]/deg[c]) + bl2 + Wr2*h1[c]); out = Wlin.h2+blin
__global__ void k_final(const float* __restrict__ aggC, const float* __restrict__ agg2,
                        const int* __restrict__ degC, const int* __restrict__ flag,
                        const int* __restrict__ cpos, const float* __restrict__ Wl2,
                        const float* __restrict__ bl2, const float* __restrict__ Wr2,
                        const float* __restrict__ Wlin, const float* __restrict__ blin,
                        float* __restrict__ out) {
  int lane = threadIdx.x & 63;
  int g = (blockIdx.x * blockDim.x + threadIdx.x) >> 6;
  if (g >= NG) return;
  int c  = g * NPG + cpos[g];
  int sl = flag[c] >> 2;
  float dg = (float)degC[sl];
  if (dg < 1.f) dg = 1.f;
  float m  = agg2[(size_t)g * D + lane] / dg;
  float hc = aggC[(size_t)sl * D + lane];
  float h  = bl2[lane];
#pragma unroll
  for (int k = 0; k < D; k++) {
    h += Wl2[lane * D + k] * __shfl(m, k) + Wr2[lane * D + k] * __shfl(hc, k);
  }
  h = fmaxf(h, 0.f);
  float p = Wlin[lane] * h;
#pragma unroll
  for (int off = 32; off; off >>= 1) p += __shfl_down(p, off);
  if (lane == 0) out[g] = p + blin[0];
}

extern "C" void kernel_launch(void* const* d_in, const int* in_sizes, int n_in,
                              void* d_out, int out_size, void* d_ws, size_t ws_size,
                              hipStream_t stream) {
  const float* x    = (const float*)d_in[0];
  const int*   ei   = (const int*)d_in[1];
  const int*   srcI = ei;          // edge_index[0]
  const int*   dstI = ei + NE;     // edge_index[1]
  const int*   cpos = (const int*)d_in[3];
  const float* Wl1  = (const float*)d_in[4];
  const float* bl1  = (const float*)d_in[5];
  const float* Wr1  = (const float*)d_in[6];
  const float* Wl2  = (const float*)d_in[7];
  const float* bl2  = (const float*)d_in[8];
  const float* Wr2  = (const float*)d_in[9];
  const float* Wlin = (const float*)d_in[10];
  const float* blin = (const float*)d_in[11];
  float* out = (float*)d_out;

  char* ws = (char*)d_ws;
  float* aggC = (float*)(ws + OFF_AGGC);
  float* agg2 = (float*)(ws + OFF_AGG2);
  int*   flag = (int*)(ws + OFF_FLAG);
  int*   degC = (int*)(ws + OFF_DEGC);
  int*   cnt  = (int*)(ws + OFF_CNT);
  int*   nlst = (int*)(ws + OFF_NODE);
  int2*  elst = (int2*)(ws + OFF_ELIST);

  hipMemsetAsync(ws + OFF_AGG2, 0, MEMSET_BYTES, stream);
  k_init<<<2, 256, 0, stream>>>(cpos, flag);
  k_mark<<<2048, 256, 0, stream>>>(srcI, dstI, flag, elst, cnt);
  k_compact<<<(NN + 255) / 256, 256, 0, stream>>>(flag, nlst, aggC, cnt);
  k_agg2<<<2048, 256, 0, stream>>>(srcI, dstI, flag, x, aggC, degC);
  k_sage1<<<512, 256, 0, stream>>>(x, nlst, degC, aggC, Wl1, bl1, Wr1, cnt);
  k_agg1<<<256, 256, 0, stream>>>(elst, flag, aggC, agg2, cnt);
  k_final<<<(NG * 64 + 255) / 256, 256, 0, stream>>>(aggC, agg2, degC, flag, cpos,
                                                     Wl2, bl2, Wr2, Wlin, blin, out);
}